// Round 11
// baseline (21.489 us; speedup 1.0000x reference)
//
#include <hip/hip_runtime.h>
#include <math.h>

// B=8, PN=8 -> BP=64; PL=511 -> L=512; NV=2; H=8; DK=DV=32; D=256; DM=512; HID=1024.
namespace {
constexpr int L   = 512;
constexpr int D   = 256;
constexpr int DM  = 512;
constexpr int HID = 1024;
constexpr float INV_SQRT_DK = 0.17677669529663687f;  // 1/sqrt(32)

// thetas[j] = 1000^(-j/16), precomputed literals
__device__ __constant__ float THETA[16] = {
  1.0f,           0.64938163f,  0.42169650f,  0.27384196f,
  0.17782794f,    0.11547820f,  0.074989421f, 0.048696753f,
  0.031622777f,   0.020535250f, 0.013335214f, 0.0086596432f,
  0.0056234133f,  0.0036517412f,0.0023713737f,0.0015399265f };

// ---------------- K1: attention, one block per (bp, head) ---------------- (unchanged)
__global__ __launch_bounds__(512, 2)
void k_attn(const float* __restrict__ x, const float* __restrict__ t,
            const int* __restrict__ mask, const float* __restrict__ emb,
            const float* __restrict__ Wq, const float* __restrict__ Wk,
            const float* __restrict__ Wv, float* __restrict__ last) {
  const int bp = blockIdx.x & 63, h = blockIdx.x >> 6;
  const int tid = threadIdx.x, lane = tid & 63, wid = tid >> 6;

  __shared__ float s_q[32];       // qre [0..16), qim [16..32)
  __shared__ float s_pq[4][16];   // P0, P1, Q0, Q1
  __shared__ float red[24];

  const int   m0 = mask[bp * L];
  const float tl = t[bp * L + tid];
  const int   ml = mask[bp * L + tid];
  float xl0, xl1;
  if (tid == 0) { xl0 = emb[0]; xl1 = emb[1]; }
  else {
    const float2 v = reinterpret_cast<const float2*>(x)[bp * (L - 1) + tid - 1];
    xl0 = v.x; xl1 = v.y;
  }

  if (tid < 16) {  // RoPE'd, pre-scaled query for this head
    const float t0v = t[bp * L];
    const float e0 = emb[0], e1 = emb[1];
    const float re = e0 * Wq[h * 32 + 2 * tid]     + e1 * Wq[256 + h * 32 + 2 * tid];
    const float im = e0 * Wq[h * 32 + 2 * tid + 1] + e1 * Wq[256 + h * 32 + 2 * tid + 1];
    float s0, c0;
    __sincosf(t0v * THETA[tid], &s0, &c0);
    s_q[tid]      = (re * c0 - im * s0) * INV_SQRT_DK;
    s_q[16 + tid] = (re * s0 + im * c0) * INV_SQRT_DK;
  }
  __syncthreads();
  if (tid < 16) {  // P/Q constants (fold q into Wk)
    const int j = tid;
    const float qre = s_q[j], qim = s_q[16 + j];
    const float k0  = Wk[h * 32 + 2 * j],       k01 = Wk[h * 32 + 2 * j + 1];
    const float k1  = Wk[256 + h * 32 + 2 * j], k11 = Wk[256 + h * 32 + 2 * j + 1];
    s_pq[0][j] = qre * k0 + qim * k01;   // P0
    s_pq[1][j] = qre * k1 + qim * k11;   // P1
    s_pq[2][j] = qim * k0 - qre * k01;   // Q0
    s_pq[3][j] = qim * k1 - qre * k11;   // Q1
  }
  __syncthreads();

  float A = 0.f, B = 0.f;
  #pragma unroll
  for (int j = 0; j < 16; ++j) {
    float sn, cs;
    __sincosf(tl * THETA[j], &sn, &cs);
    A = fmaf(cs, s_pq[0][j], A); A = fmaf(sn, s_pq[2][j], A);
    B = fmaf(cs, s_pq[1][j], B); B = fmaf(sn, s_pq[3][j], B);
  }
  const float sc = xl0 * A + xl1 * B;

  // masked softmax weight (no max pass: scores bounded; m0==0 -> uniform)
  const float e = (m0 == 0) ? 1.f : (ml ? __expf(sc) : 0.f);

  float se = e, s0a = e * xl0, s1a = e * xl1;
  #pragma unroll
  for (int o = 32; o; o >>= 1) {
    se  += __shfl_xor(se, o);
    s0a += __shfl_xor(s0a, o);
    s1a += __shfl_xor(s1a, o);
  }
  if (lane == 0) { red[wid] = se; red[8 + wid] = s0a; red[16 + wid] = s1a; }
  __syncthreads();
  se = 0.f; s0a = 0.f; s1a = 0.f;
  #pragma unroll
  for (int w = 0; w < 8; ++w) { se += red[w]; s0a += red[8 + w]; s1a += red[16 + w]; }

  if (tid < 32)
    last[bp * 256 + h * 32 + tid] =
        (s0a * Wv[h * 32 + tid] + s1a * Wv[256 + h * 32 + tid]) / se;
}

// ---------------- K2: fused FFN1+FFN2, 2 blocks/CU ----------------
// grid 512: kt = bid&31 (32 hid cols; same-kt blocks share an XCD), mt = bid>>5.
// 512 threads: W1 phase rg = tid>>5 owns 16 k-rows, col = tid&31.
//              W2 phase kg = tid>>6 owns 4 k-rows, cols (tid&63)*4.
__global__ __launch_bounds__(512, 4)
void k_ffn(const float* __restrict__ last, const float* __restrict__ W1,
           const float* __restrict__ b1, const float* __restrict__ W2,
           float* __restrict__ partial) {
  const int kt = blockIdx.x & 31, mt = blockIdx.x >> 5;
  const int tid = threadIdx.x;

  __shared__ float ls[4][256];        // last tile (4 bp rows)
  __shared__ float s_p1[16][4][32];   // W1 rowgroup-partials (8 KB)
  __shared__ float hs[4][32];         // relu'd hidden tile
  __shared__ float s_p2[8][4][256];   // W2 kgroup-partials (32 KB)

  // ---- issue W1 weight loads FIRST (independent of `last`) ----
  const int col = tid & 31, rg = tid >> 5;      // rg 0..15: rows rg*16..+16
  const int j = kt * 32 + col;
  float w1r[16];
  {
    const float* w1p = W1 + (size_t)(rg * 16) * HID + j;
    #pragma unroll
    for (int g = 0; g < 16; ++g) w1r[g] = w1p[(size_t)g * HID];
  }

  // stage `last` tile (latency overlaps W1 loads)
  #pragma unroll
  for (int q = 0; q < 2; ++q) {
    const int idx = tid + q * 512;
    ls[idx >> 8][idx & 255] = last[(mt * 4 + (idx >> 8)) * 256 + (idx & 255)];
  }
  __syncthreads();

  // ---- W1 fma: 16 k-rows x 4 bp rows (ls reads broadcast within wave) ----
  {
    float a0 = 0.f, a1 = 0.f, a2 = 0.f, a3 = 0.f;
    #pragma unroll
    for (int g = 0; g < 16; ++g) {
      const int rr = rg * 16 + g;
      const float w = w1r[g];
      a0 = fmaf(ls[0][rr], w, a0);
      a1 = fmaf(ls[1][rr], w, a1);
      a2 = fmaf(ls[2][rr], w, a2);
      a3 = fmaf(ls[3][rr], w, a3);
    }
    s_p1[rg][0][col] = a0; s_p1[rg][1][col] = a1;
    s_p1[rg][2][col] = a2; s_p1[rg][3][col] = a3;
  }

  // ---- issue W2 loads before the combine barriers ----
  const int kg = tid >> 6, c4 = (tid & 63) * 4;  // kg 0..7: k-rows kg*4..+4
  float4 w2r[4];
  {
    const float* w2p = W2 + (size_t)(kt * 32 + kg * 4) * D + c4;
    #pragma unroll
    for (int k = 0; k < 4; ++k)
      w2r[k] = *reinterpret_cast<const float4*>(w2p + (size_t)k * D);
  }
  __syncthreads();

  // ---- combine + bias + relu -> hs[4][32] ----
  if (tid < 128) {
    const int r = tid >> 5, k = tid & 31;
    float hv = b1[kt * 32 + k];
    #pragma unroll
    for (int g = 0; g < 16; ++g) hv += s_p1[g][r][k];
    hs[r][k] = fmaxf(hv, 0.f);
  }
  __syncthreads();

  // ---- W2 fma: 4 k-rows x 4 bp x 4 cols ----
  {
    float hr[4][4];
    #pragma unroll
    for (int r = 0; r < 4; ++r)
      *reinterpret_cast<float4*>(&hr[r][0]) =
          *reinterpret_cast<const float4*>(&hs[r][kg * 4]);
    float4 c0 = {0,0,0,0}, c1 = {0,0,0,0}, c2 = {0,0,0,0}, c3 = {0,0,0,0};
    #pragma unroll
    for (int k = 0; k < 4; ++k) {
      const float4 wv = w2r[k];
      c0.x = fmaf(hr[0][k], wv.x, c0.x); c0.y = fmaf(hr[0][k], wv.y, c0.y);
      c0.z = fmaf(hr[0][k], wv.z, c0.z); c0.w = fmaf(hr[0][k], wv.w, c0.w);
      c1.x = fmaf(hr[1][k], wv.x, c1.x); c1.y = fmaf(hr[1][k], wv.y, c1.y);
      c1.z = fmaf(hr[1][k], wv.z, c1.z); c1.w = fmaf(hr[1][k], wv.w, c1.w);
      c2.x = fmaf(hr[2][k], wv.x, c2.x); c2.y = fmaf(hr[2][k], wv.y, c2.y);
      c2.z = fmaf(hr[2][k], wv.z, c2.z); c2.w = fmaf(hr[2][k], wv.w, c2.w);
      c3.x = fmaf(hr[3][k], wv.x, c3.x); c3.y = fmaf(hr[3][k], wv.y, c3.y);
      c3.z = fmaf(hr[3][k], wv.z, c3.z); c3.w = fmaf(hr[3][k], wv.w, c3.w);
    }
    *reinterpret_cast<float4*>(&s_p2[kg][0][c4]) = c0;
    *reinterpret_cast<float4*>(&s_p2[kg][1][c4]) = c1;
    *reinterpret_cast<float4*>(&s_p2[kg][2][c4]) = c2;
    *reinterpret_cast<float4*>(&s_p2[kg][3][c4]) = c3;
  }
  __syncthreads();

  // ---- final combine over 8 kgroups; float2 store ----
  {
    const int r = tid >> 7, ci = (tid & 127) * 2;
    float v0 = 0.f, v1 = 0.f;
    #pragma unroll
    for (int g = 0; g < 8; ++g) { v0 += s_p2[g][r][ci]; v1 += s_p2[g][r][ci + 1]; }
    *reinterpret_cast<float2*>(
        &partial[(size_t)(kt * 64 + mt * 4 + r) * 256 + ci]) = make_float2(v0, v1);
  }
}

// ---------------- K3: reduce partials + residual + LN + out tile, 2 blocks/CU ----------------
// grid 512: ct = bid&7 (64 Wo cols; same-ct on same XCD), bp = bid>>3.
__global__ __launch_bounds__(512, 4)
void k_tail(const float* __restrict__ last, const float* __restrict__ partial,
            const float* __restrict__ b2, const float* __restrict__ ln_g,
            const float* __restrict__ ln_b, const float* __restrict__ Wo,
            float* __restrict__ out) {
  const int ct = blockIdx.x & 7, bp = blockIdx.x >> 3;
  const int tid = threadIdx.x, lane = tid & 63, wid = tid >> 6;

  __shared__ float s_y[2][256];
  __shared__ float s_yn[256];
  __shared__ float s_op[16][64];
  __shared__ float red[8];

  // ---- issue Wo loads FIRST: kq = tid>>5 owns rows kq*16..+16, col pair ----
  const int cp = (tid & 31) * 2, kq = tid >> 5;   // kq 0..15
  float2 wor[16];
  {
    const float* wop = Wo + (size_t)(kq * 16) * DM + ct * 64 + cp;
    #pragma unroll
    for (int i = 0; i < 16; ++i)
      wor[i] = *reinterpret_cast<const float2*>(wop + (size_t)i * DM);
  }

  // Phase A: partial reduce over 32 kt-slices, 2-way split
  {
    const int col = tid & 255, kh = tid >> 8;
    float acc = kh ? 0.f : (last[bp * 256 + col] + b2[col]);
    #pragma unroll
    for (int kt = kh * 16; kt < kh * 16 + 16; ++kt)
      acc += partial[(size_t)(kt * 64 + bp) * 256 + col];
    s_y[kh][col] = acc;
  }
  __syncthreads();

  // Phase B: layernorm over 256
  float y = 0.f;
  if (tid < 256) y = s_y[0][tid] + s_y[1][tid];
  float ssum = (tid < 256) ? y : 0.f, ssq = (tid < 256) ? y * y : 0.f;
  #pragma unroll
  for (int o = 32; o; o >>= 1) { ssum += __shfl_xor(ssum, o); ssq += __shfl_xor(ssq, o); }
  if (tid < 256 && lane == 0) { red[wid] = ssum; red[4 + wid] = ssq; }
  __syncthreads();
  ssum = red[0] + red[1] + red[2] + red[3];
  ssq  = red[4] + red[5] + red[6] + red[7];
  const float mu   = ssum / 256.f;
  const float var  = ssq / 256.f - mu * mu;
  const float rstd = rsqrtf(var + 1e-5f);
  if (tid < 256) s_yn[tid] = (y - mu) * rstd * ln_g[tid] + ln_b[tid];
  __syncthreads();

  // Phase C: out tile (64 cols), weights already in regs, 16-way K-split
  {
    float f0 = 0.f, f1 = 0.f;
    #pragma unroll
    for (int i = 0; i < 16; ++i) {
      const float yv = s_yn[kq * 16 + i];
      f0 = fmaf(yv, wor[i].x, f0);
      f1 = fmaf(yv, wor[i].y, f1);
    }
    s_op[kq][cp] = f0; s_op[kq][cp + 1] = f1;
  }
  __syncthreads();
  if (tid < 64) {
    float a = 0.f;
    #pragma unroll
    for (int k = 0; k < 16; ++k) a += s_op[k][tid];
    out[(size_t)bp * DM + ct * 64 + tid] = a;
  }
}
}  // namespace

extern "C" void kernel_launch(void* const* d_in, const int* in_sizes, int n_in,
                              void* d_out, int out_size, void* d_ws, size_t ws_size,
                              hipStream_t stream) {
  const float* x    = (const float*)d_in[0];
  const float* t    = (const float*)d_in[1];
  const int*   mask = (const int*)  d_in[2];
  const float* emb  = (const float*)d_in[3];
  const float* Wq   = (const float*)d_in[4];
  const float* Wk   = (const float*)d_in[5];
  const float* Wv   = (const float*)d_in[6];
  const float* Wo   = (const float*)d_in[7];
  const float* lng  = (const float*)d_in[8];
  const float* lnb  = (const float*)d_in[9];
  const float* W1   = (const float*)d_in[10];
  const float* b1   = (const float*)d_in[11];
  const float* W2   = (const float*)d_in[12];
  const float* b2   = (const float*)d_in[13];
  float* out = (float*)d_out;

  float* ws      = (float*)d_ws;
  float* last    = ws;            // 64*256 floats
  float* partial = ws + 16384;    // 32*64*256 floats (2 MB)

  k_attn<<<512, 512, 0, stream>>>(x, t, mask, emb, Wq, Wk, Wv, last);
  k_ffn <<<512, 512, 0, stream>>>(last, W1, b1, W2, partial);
  k_tail<<<512, 512, 0, stream>>>(last, partial, b2, lng, lnb, Wo, out);
}

// Round 12
// 18.563 us; speedup vs baseline: 1.1576x; 1.1576x over previous
//
#include <hip/hip_runtime.h>
#include <math.h>

// B=8, PN=8 -> BP=64; PL=511 -> L=512; NV=2; H=8; DK=DV=32; D=256; DM=512; HID=1024.
namespace {
constexpr int L   = 512;
constexpr int D   = 256;
constexpr int DM  = 512;
constexpr int HID = 1024;
constexpr float INV_SQRT_DK = 0.17677669529663687f;  // 1/sqrt(32)

// thetas[j] = 1000^(-j/16), precomputed literals
__device__ __constant__ float THETA[16] = {
  1.0f,           0.64938163f,  0.42169650f,  0.27384196f,
  0.17782794f,    0.11547820f,  0.074989421f, 0.048696753f,
  0.031622777f,   0.020535250f, 0.013335214f, 0.0086596432f,
  0.0056234133f,  0.0036517412f,0.0023713737f,0.0015399265f };

// ---------------- K1: attention, one block per (bp, head) ----------------
// Factored scores: sc(pos) = xl0*A + xl1*B, A = sum_j c_j*P0_j + s_j*Q0_j.
__global__ __launch_bounds__(512, 2)
void k_attn(const float* __restrict__ x, const float* __restrict__ t,
            const int* __restrict__ mask, const float* __restrict__ emb,
            const float* __restrict__ Wq, const float* __restrict__ Wk,
            const float* __restrict__ Wv, float* __restrict__ last) {
  const int bp = blockIdx.x & 63, h = blockIdx.x >> 6;
  const int tid = threadIdx.x, lane = tid & 63, wid = tid >> 6;

  __shared__ float s_q[32];       // qre [0..16), qim [16..32)
  __shared__ float s_pq[4][16];   // P0, P1, Q0, Q1
  __shared__ float red[24];

  const int   m0 = mask[bp * L];
  const float tl = t[bp * L + tid];
  const int   ml = mask[bp * L + tid];
  float xl0, xl1;
  if (tid == 0) { xl0 = emb[0]; xl1 = emb[1]; }
  else {
    const float2 v = reinterpret_cast<const float2*>(x)[bp * (L - 1) + tid - 1];
    xl0 = v.x; xl1 = v.y;
  }

  if (tid < 16) {  // RoPE'd, pre-scaled query for this head
    const float t0v = t[bp * L];
    const float e0 = emb[0], e1 = emb[1];
    const float re = e0 * Wq[h * 32 + 2 * tid]     + e1 * Wq[256 + h * 32 + 2 * tid];
    const float im = e0 * Wq[h * 32 + 2 * tid + 1] + e1 * Wq[256 + h * 32 + 2 * tid + 1];
    float s0, c0;
    __sincosf(t0v * THETA[tid], &s0, &c0);
    s_q[tid]      = (re * c0 - im * s0) * INV_SQRT_DK;
    s_q[16 + tid] = (re * s0 + im * c0) * INV_SQRT_DK;
  }
  __syncthreads();
  if (tid < 16) {  // P/Q constants (fold q into Wk)
    const int j = tid;
    const float qre = s_q[j], qim = s_q[16 + j];
    const float k0  = Wk[h * 32 + 2 * j],       k01 = Wk[h * 32 + 2 * j + 1];
    const float k1  = Wk[256 + h * 32 + 2 * j], k11 = Wk[256 + h * 32 + 2 * j + 1];
    s_pq[0][j] = qre * k0 + qim * k01;   // P0
    s_pq[1][j] = qre * k1 + qim * k11;   // P1
    s_pq[2][j] = qim * k0 - qre * k01;   // Q0
    s_pq[3][j] = qim * k1 - qre * k11;   // Q1
  }
  __syncthreads();

  float A = 0.f, B = 0.f;
  #pragma unroll
  for (int j = 0; j < 16; ++j) {
    float sn, cs;
    __sincosf(tl * THETA[j], &sn, &cs);
    A = fmaf(cs, s_pq[0][j], A); A = fmaf(sn, s_pq[2][j], A);
    B = fmaf(cs, s_pq[1][j], B); B = fmaf(sn, s_pq[3][j], B);
  }
  const float sc = xl0 * A + xl1 * B;

  // masked softmax weight (no max pass: scores bounded; m0==0 -> uniform)
  const float e = (m0 == 0) ? 1.f : (ml ? __expf(sc) : 0.f);

  float se = e, s0a = e * xl0, s1a = e * xl1;
  #pragma unroll
  for (int o = 32; o; o >>= 1) {
    se  += __shfl_xor(se, o);
    s0a += __shfl_xor(s0a, o);
    s1a += __shfl_xor(s1a, o);
  }
  if (lane == 0) { red[wid] = se; red[8 + wid] = s0a; red[16 + wid] = s1a; }
  __syncthreads();
  se = 0.f; s0a = 0.f; s1a = 0.f;
  #pragma unroll
  for (int w = 0; w < 8; ++w) { se += red[w]; s0a += red[8 + w]; s1a += red[16 + w]; }

  // attn@V == ((attn@xx)@Wv): NV=2, V carries no RoPE
  if (tid < 32)
    last[bp * 256 + h * 32 + tid] =
        (s0a * Wv[h * 32 + tid] + s1a * Wv[256 + h * 32 + tid]) / se;
}

// ---------------- K2: fused FFN1+FFN2, wave-cooperative ----------------
// grid 256 = 1 block/CU: kt = bid&15, mt = bid>>4. 512 threads = 8 waves.
// vmcnt ordering: `last` loads issued FIRST so the LDS-staging write waits
// only on them, leaving the 32 W1 loads in flight across the barrier.
__global__ __launch_bounds__(512, 1)
void k_ffn(const float* __restrict__ last, const float* __restrict__ W1,
           const float* __restrict__ b1, const float* __restrict__ W2,
           float* __restrict__ partial) {
  const int kt = blockIdx.x & 15, mt = blockIdx.x >> 4;
  const int tid = threadIdx.x, lane = tid & 63, w = tid >> 6;

  __shared__ float ls[4][256];        // last tile (4 bp rows)
  __shared__ float s_p1[8][4][64];    // W1 wave-partials
  __shared__ float hs[4][64];         // relu'd hidden tile
  __shared__ float s_p2[8][4][256];   // W2 wave-partials (32 KB)

  // ---- issue the 2 `last` loads FIRST (oldest in vmcnt queue) ----
  float lsr[2];
  #pragma unroll
  for (int q = 0; q < 2; ++q) {
    const int idx = tid + q * 512;
    lsr[q] = last[(mt * 4 + (idx >> 8)) * 256 + (idx & 255)];
  }

  // ---- then the 32 W1 weight loads (stay in flight across the barrier) ----
  const int j = kt * 64 + lane;
  float w1r[32];
  {
    const float* w1p = W1 + (size_t)(w * 32) * HID + j;
    #pragma unroll
    for (int g = 0; g < 32; ++g) w1r[g] = w1p[(size_t)g * HID];
  }

  // ---- LDS-stage `last` (waits only on the 2 oldest loads) ----
  #pragma unroll
  for (int q = 0; q < 2; ++q) {
    const int idx = tid + q * 512;
    ls[idx >> 8][idx & 255] = lsr[q];
  }
  __syncthreads();

  // ---- W1 fma: col j, wave w rows w*32..+32, 4 row-accumulators ----
  {
    float a0 = 0.f, a1 = 0.f, a2 = 0.f, a3 = 0.f;
    #pragma unroll
    for (int g = 0; g < 8; ++g) {
      const float4 l0 = *reinterpret_cast<const float4*>(&ls[0][w * 32 + g * 4]);
      const float4 l1 = *reinterpret_cast<const float4*>(&ls[1][w * 32 + g * 4]);
      const float4 l2 = *reinterpret_cast<const float4*>(&ls[2][w * 32 + g * 4]);
      const float4 l3 = *reinterpret_cast<const float4*>(&ls[3][w * 32 + g * 4]);
      a0 = fmaf(l0.x, w1r[g*4+0], a0); a0 = fmaf(l0.y, w1r[g*4+1], a0);
      a0 = fmaf(l0.z, w1r[g*4+2], a0); a0 = fmaf(l0.w, w1r[g*4+3], a0);
      a1 = fmaf(l1.x, w1r[g*4+0], a1); a1 = fmaf(l1.y, w1r[g*4+1], a1);
      a1 = fmaf(l1.z, w1r[g*4+2], a1); a1 = fmaf(l1.w, w1r[g*4+3], a1);
      a2 = fmaf(l2.x, w1r[g*4+0], a2); a2 = fmaf(l2.y, w1r[g*4+1], a2);
      a2 = fmaf(l2.z, w1r[g*4+2], a2); a2 = fmaf(l2.w, w1r[g*4+3], a2);
      a3 = fmaf(l3.x, w1r[g*4+0], a3); a3 = fmaf(l3.y, w1r[g*4+1], a3);
      a3 = fmaf(l3.z, w1r[g*4+2], a3); a3 = fmaf(l3.w, w1r[g*4+3], a3);
    }
    s_p1[w][0][lane] = a0; s_p1[w][1][lane] = a1;
    s_p1[w][2][lane] = a2; s_p1[w][3][lane] = a3;
  }

  // ---- issue W2 weight loads before the combine barriers ----
  float4 w2r[8];
  {
    const float* w2p = W2 + (size_t)(kt * 64 + w * 8) * D + lane * 4;
    #pragma unroll
    for (int k = 0; k < 8; ++k)
      w2r[k] = *reinterpret_cast<const float4*>(w2p + (size_t)k * D);
  }
  __syncthreads();

  // ---- combine + bias + relu -> hs[4][64] ----
  if (tid < 256) {
    const int r = tid >> 6, k = tid & 63;
    float hv = b1[kt * 64 + k];
    #pragma unroll
    for (int ww = 0; ww < 8; ++ww) hv += s_p1[ww][r][k];
    hs[r][k] = fmaxf(hv, 0.f);
  }
  __syncthreads();

  // ---- W2 fma: wave w k-rows w*8..+8; cols lane*4 ----
  {
    float hr[4][8];
    #pragma unroll
    for (int r = 0; r < 4; ++r) {
      *reinterpret_cast<float4*>(&hr[r][0]) = *reinterpret_cast<const float4*>(&hs[r][w * 8]);
      *reinterpret_cast<float4*>(&hr[r][4]) = *reinterpret_cast<const float4*>(&hs[r][w * 8 + 4]);
    }
    float4 c0 = {0,0,0,0}, c1 = {0,0,0,0}, c2 = {0,0,0,0}, c3 = {0,0,0,0};
    #pragma unroll
    for (int k = 0; k < 8; ++k) {
      const float4 wv = w2r[k];
      c0.x = fmaf(hr[0][k], wv.x, c0.x); c0.y = fmaf(hr[0][k], wv.y, c0.y);
      c0.z = fmaf(hr[0][k], wv.z, c0.z); c0.w = fmaf(hr[0][k], wv.w, c0.w);
      c1.x = fmaf(hr[1][k], wv.x, c1.x); c1.y = fmaf(hr[1][k], wv.y, c1.y);
      c1.z = fmaf(hr[1][k], wv.z, c1.z); c1.w = fmaf(hr[1][k], wv.w, c1.w);
      c2.x = fmaf(hr[2][k], wv.x, c2.x); c2.y = fmaf(hr[2][k], wv.y, c2.y);
      c2.z = fmaf(hr[2][k], wv.z, c2.z); c2.w = fmaf(hr[2][k], wv.w, c2.w);
      c3.x = fmaf(hr[3][k], wv.x, c3.x); c3.y = fmaf(hr[3][k], wv.y, c3.y);
      c3.z = fmaf(hr[3][k], wv.z, c3.z); c3.w = fmaf(hr[3][k], wv.w, c3.w);
    }
    *reinterpret_cast<float4*>(&s_p2[w][0][lane * 4]) = c0;
    *reinterpret_cast<float4*>(&s_p2[w][1][lane * 4]) = c1;
    *reinterpret_cast<float4*>(&s_p2[w][2][lane * 4]) = c2;
    *reinterpret_cast<float4*>(&s_p2[w][3][lane * 4]) = c3;
  }
  __syncthreads();

  // ---- final combine over 8 wave-partials; float2 store ----
  {
    const int r = tid >> 7, c0i = (tid & 127) * 2;
    float v0 = 0.f, v1 = 0.f;
    #pragma unroll
    for (int ww = 0; ww < 8; ++ww) {
      v0 += s_p2[ww][r][c0i];
      v1 += s_p2[ww][r][c0i + 1];
    }
    *reinterpret_cast<float2*>(
        &partial[(size_t)(kt * 64 + mt * 4 + r) * 256 + c0i]) = make_float2(v0, v1);
  }
}

// ---------------- K3: reduce partials + residual + LN + out tile ----------------
// grid 256 = 1 block/CU: ct = bid&3, bp = bid>>2; 512 threads.
// vmcnt ordering: partial/last loads issued FIRST, Wo batch second.
__global__ __launch_bounds__(512, 1)
void k_tail(const float* __restrict__ last, const float* __restrict__ partial,
            const float* __restrict__ b2, const float* __restrict__ ln_g,
            const float* __restrict__ ln_b, const float* __restrict__ Wo,
            float* __restrict__ out) {
  const int ct = blockIdx.x & 3, bp = blockIdx.x >> 2;
  const int tid = threadIdx.x, lane = tid & 63, wid = tid >> 6;

  __shared__ float s_y[2][256];
  __shared__ float s_yn[256];
  __shared__ float s_op[8][128];
  __shared__ float red[8];

  // ---- issue phase-A loads FIRST: last/b2 + 8 partial slices ----
  const int colA = tid & 255, khh = tid >> 8;
  float base = khh ? 0.f : (last[bp * 256 + colA] + b2[colA]);
  float pr[8];
  #pragma unroll
  for (int k = 0; k < 8; ++k)
    pr[k] = partial[(size_t)((khh * 8 + k) * 64 + bp) * 256 + colA];

  // ---- then the 32 Wo loads (in flight across phases A+B) ----
  const int l6 = tid & 63, kq = tid >> 6;
  const int c0 = ct * 128 + 2 * l6;
  float2 wor[32];
  {
    const float* wop = Wo + (size_t)(kq * 32) * DM + c0;
    #pragma unroll
    for (int i = 0; i < 32; ++i)
      wor[i] = *reinterpret_cast<const float2*>(wop + (size_t)i * DM);
  }

  // Phase A: partial reduce (waits only on the oldest loads)
  {
    float acc = base;
    #pragma unroll
    for (int k = 0; k < 8; ++k) acc += pr[k];
    s_y[khh][colA] = acc;
  }
  __syncthreads();

  // Phase B: layernorm over 256
  float y = 0.f;
  if (tid < 256) y = s_y[0][tid] + s_y[1][tid];
  float ssum = (tid < 256) ? y : 0.f, ssq = (tid < 256) ? y * y : 0.f;
  #pragma unroll
  for (int o = 32; o; o >>= 1) { ssum += __shfl_xor(ssum, o); ssq += __shfl_xor(ssq, o); }
  if (tid < 256 && lane == 0) { red[wid] = ssum; red[4 + wid] = ssq; }
  __syncthreads();
  ssum = red[0] + red[1] + red[2] + red[3];
  ssq  = red[4] + red[5] + red[6] + red[7];
  const float mu   = ssum / 256.f;
  const float var  = ssq / 256.f - mu * mu;
  const float rstd = rsqrtf(var + 1e-5f);
  if (tid < 256) s_yn[tid] = (y - mu) * rstd * ln_g[tid] + ln_b[tid];
  __syncthreads();

  // Phase C: out tile, weights already in regs
  {
    float f0 = 0.f, f1 = 0.f;
    #pragma unroll
    for (int i = 0; i < 32; ++i) {
      const float yv = s_yn[kq * 32 + i];
      f0 = fmaf(yv, wor[i].x, f0);
      f1 = fmaf(yv, wor[i].y, f1);
    }
    s_op[kq][2 * l6] = f0; s_op[kq][2 * l6 + 1] = f1;
  }
  __syncthreads();
  if (tid < 128) {
    float a = 0.f;
    #pragma unroll
    for (int k = 0; k < 8; ++k) a += s_op[k][tid];
    out[(size_t)bp * DM + ct * 128 + tid] = a;
  }
}
}  // namespace

extern "C" void kernel_launch(void* const* d_in, const int* in_sizes, int n_in,
                              void* d_out, int out_size, void* d_ws, size_t ws_size,
                              hipStream_t stream) {
  const float* x    = (const float*)d_in[0];
  const float* t    = (const float*)d_in[1];
  const int*   mask = (const int*)  d_in[2];
  const float* emb  = (const float*)d_in[3];
  const float* Wq   = (const float*)d_in[4];
  const float* Wk   = (const float*)d_in[5];
  const float* Wv   = (const float*)d_in[6];
  const float* Wo   = (const float*)d_in[7];
  const float* lng  = (const float*)d_in[8];
  const float* lnb  = (const float*)d_in[9];
  const float* W1   = (const float*)d_in[10];
  const float* b1   = (const float*)d_in[11];
  const float* W2   = (const float*)d_in[12];
  const float* b2   = (const float*)d_in[13];
  float* out = (float*)d_out;

  float* ws      = (float*)d_ws;
  float* last    = ws;            // 64*256 floats
  float* partial = ws + 16384;    // 16*64*256 floats

  k_attn<<<512, 512, 0, stream>>>(x, t, mask, emb, Wq, Wk, Wv, last);
  k_ffn <<<256, 512, 0, stream>>>(last, W1, b1, W2, partial);
  k_tail<<<256, 512, 0, stream>>>(last, partial, b2, lng, lnb, Wo, out);
}